// Round 8
// baseline (749.472 us; speedup 1.0000x reference)
//
#include <hip/hip_runtime.h>
#include <cfloat>

#define EMB 300
#define TT 256      // T (word/output GRU hidden, also S)
#define SS 256      // S
#define KK 10
#define LL 128
#define NN 8192
#define G3 768      // 3*T
#define PKN (512 * 192)   // u32 count of one packed whh (per-scan)

typedef _Float16 half2_t __attribute__((ext_vector_type(2)));

#if __has_builtin(__builtin_amdgcn_fdot2)
#define FDOT2(a, b, c) __builtin_amdgcn_fdot2((a), (b), (c), false)
#else
#define FDOT2(a, b, c) ((c) + (float)(a).x * (float)(b).x + (float)(a).y * (float)(b).y)
#endif

__device__ __forceinline__ float sigmoidf_(float x) {
    return __builtin_amdgcn_rcpf(1.0f + __expf(-x));
}
__device__ __forceinline__ float tanhf_(float x) {
    return 2.0f * __builtin_amdgcn_rcpf(1.0f + __expf(-2.0f * x)) - 1.0f;
}

// ---------- Kernel P: pack whh f32 -> f16-pair u32, per-thread-consumption order ----
__global__ void k_pack(const float* __restrict__ whhF, const float* __restrict__ whhB,
                       const float* __restrict__ whhO, unsigned int* __restrict__ pF,
                       unsigned int* __restrict__ pB, unsigned int* __restrict__ pO) {
    const int m = blockIdx.y;
    const float* src = m == 0 ? whhF : (m == 1 ? whhB : whhO);
    unsigned int* dst = m == 0 ? pF : (m == 1 ? pB : pO);
    const int g = blockIdx.x * 1024 + threadIdx.x;  // [0, 98304)
    const int tid_s = g / 192;
    const int idx = g - tid_s * 192;
    const int rr = idx >> 6;
    const int c = (idx >> 2) & 15;
    const int q = idx & 3;
    const int grp = tid_s >> 8;
    const int r3 = tid_s & 255;
    const int row = rr * 256 + r3;
    const int kb = grp * 128 + c * 8 + q * 2;
    const float e0 = src[row * 256 + kb];
    const float e1 = src[row * 256 + kb + 1];
    unsigned int lo = (unsigned int)__builtin_bit_cast(unsigned short, (_Float16)e0);
    unsigned int hi = (unsigned int)__builtin_bit_cast(unsigned short, (_Float16)e1);
    dst[g] = lo | (hi << 16);
}

// ---------- Kernel A: word-GRU input gates for both directions ----------
__global__ void k_input_gates_word(const int* __restrict__ topic, const float* __restrict__ emb,
                                   const float* __restrict__ wihF, const float* __restrict__ bihF,
                                   const float* __restrict__ wihB, const float* __restrict__ bihB,
                                   float* __restrict__ giF, float* __restrict__ giB) {
    __shared__ float4 xl[EMB / 4];  // 75
    const int l = blockIdx.x;
    const int dir = blockIdx.y;
    const float* wih = dir ? wihB : wihF;
    const float* bih = dir ? bihB : bihF;
    float* gi = dir ? giB : giF;
    const int word = topic[l];
    const float4* xrow = (const float4*)(emb + (size_t)word * EMB);
    if (threadIdx.x < EMB / 4) xl[threadIdx.x] = xrow[threadIdx.x];
    __syncthreads();
    const int j = threadIdx.x;  // 0..767
    const float4* wr = (const float4*)(wih + (size_t)j * EMB);
    float acc = bih[j];
    #pragma unroll 5
    for (int c = 0; c < EMB / 4; ++c) {
        float4 w4 = wr[c], x4 = xl[c];
        acc += w4.x * x4.x + w4.y * x4.y + w4.z * x4.z + w4.w * x4.w;
    }
    gi[l * G3 + j] = acc;
}

// ---------- Kernel C: output-GRU input gates ----------
__global__ void k_input_gates_out(const float* __restrict__ yF, const float* __restrict__ yB,
                                  const float* __restrict__ wihO, const float* __restrict__ bihO,
                                  float* __restrict__ giO) {
    __shared__ float4 yl[128];  // 512 floats = [yf | yb]
    const int l = blockIdx.x;
    if (threadIdx.x < 64) {
        yl[threadIdx.x] = ((const float4*)(yF + l * TT))[threadIdx.x];
        yl[64 + threadIdx.x] = ((const float4*)(yB + l * TT))[threadIdx.x];
    }
    __syncthreads();
    const int j = threadIdx.x;
    const float4* wr = (const float4*)(wihO + (size_t)j * 512);
    float acc = bihO[j];
    #pragma unroll 4
    for (int c = 0; c < 128; ++c) {
        float4 w4 = wr[c], x4 = yl[c];
        acc += w4.x * x4.x + w4.y * x4.y + w4.z * x4.z + w4.w * x4.w;
    }
    giO[l * G3 + j] = acc;
}

// ---------- Kernel B: GRU recurrence, one block per scan ----------
// 512 threads; grp = tid>>8 is k-half; r3 = tid&255 owns gate rows {r3, 256+r3, 512+r3}.
// Weights in 48 named uint4 values, pinned into AGPRs via "+a" asm constraints.
// (R7 post-mortem: "+v" pins fought the allocator; it had already chosen to
// park ~148 dwords in AGPRs and stream the rest from L2. Forcing ALL 192 into
// AGPRs (192 AGPR + ~64 VGPR = 256 unified budget at 2 waves/SIMD) removes the
// per-step L2 re-loads; CDNA2+ VALU can read AGPRs directly.)
#define FOR16(M) M(0) M(1) M(2) M(3) M(4) M(5) M(6) M(7) M(8) M(9) M(10) M(11) M(12) M(13) M(14) M(15)

#define LOADW(n) uint4 A##n = wp[n]; uint4 B##n = wp[16 + n]; uint4 C##n = wp[32 + n];

#define PIN4(P) asm volatile("" : "+a"(P.x), "+a"(P.y), "+a"(P.z), "+a"(P.w))
#define PINW(n) PIN4(A##n); PIN4(B##n); PIN4(C##n);

#define DOTSTEP(n) { \
    uint4 hu = h4[n]; \
    half2_t h0 = __builtin_bit_cast(half2_t, hu.x); \
    half2_t h1 = __builtin_bit_cast(half2_t, hu.y); \
    half2_t h2 = __builtin_bit_cast(half2_t, hu.z); \
    half2_t h3 = __builtin_bit_cast(half2_t, hu.w); \
    acc0 = FDOT2(__builtin_bit_cast(half2_t, A##n.x), h0, acc0); \
    acc1 = FDOT2(__builtin_bit_cast(half2_t, B##n.x), h0, acc1); \
    acc2 = FDOT2(__builtin_bit_cast(half2_t, C##n.x), h0, acc2); \
    acc0 = FDOT2(__builtin_bit_cast(half2_t, A##n.y), h1, acc0); \
    acc1 = FDOT2(__builtin_bit_cast(half2_t, B##n.y), h1, acc1); \
    acc2 = FDOT2(__builtin_bit_cast(half2_t, C##n.y), h1, acc2); \
    acc0 = FDOT2(__builtin_bit_cast(half2_t, A##n.z), h2, acc0); \
    acc1 = FDOT2(__builtin_bit_cast(half2_t, B##n.z), h2, acc1); \
    acc2 = FDOT2(__builtin_bit_cast(half2_t, C##n.z), h2, acc2); \
    acc0 = FDOT2(__builtin_bit_cast(half2_t, A##n.w), h3, acc0); \
    acc1 = FDOT2(__builtin_bit_cast(half2_t, B##n.w), h3, acc1); \
    acc2 = FDOT2(__builtin_bit_cast(half2_t, C##n.w), h3, acc2); \
}

__launch_bounds__(512, 2)
__global__ void k_gru_scan(const float* __restrict__ giA, const unsigned int* __restrict__ pA,
                           const float* __restrict__ bhhA, float* __restrict__ yA, int revA,
                           const float* __restrict__ giB_, const unsigned int* __restrict__ pB,
                           const float* __restrict__ bhhB, float* __restrict__ yB_, int revB) {
    const float* gi; const unsigned int* pk; const float* bhh; float* y; int rev;
    if (blockIdx.x == 0) { gi = giA;  pk = pA; bhh = bhhA; y = yA;  rev = revA; }
    else                 { gi = giB_; pk = pB; bhh = bhhB; y = yB_; rev = revB; }

    __shared__ __align__(16) unsigned int h_u32[TT / 2];  // h as f16 pairs (512 B)
    __shared__ float part[G3];                             // grp1 partials

    const int tid = threadIdx.x;
    const int grp = tid >> 8;
    const int r3 = tid & 255;

    // --- load packed weights into 48 named uint4 values, pin into AGPRs ---
    const uint4* wp = (const uint4*)(pk + (size_t)tid * 192);
    FOR16(LOADW)
    FOR16(PINW)

    float bias0 = 0.f, bias1 = 0.f, bias2 = 0.f;
    if (grp == 0) { bias0 = bhh[r3]; bias1 = bhh[256 + r3]; bias2 = bhh[512 + r3]; }

    for (int i = tid; i < TT / 2; i += 512) h_u32[i] = 0u;
    float hcur = 0.0f;
    __syncthreads();

    const uint4* h4 = ((const uint4*)h_u32) + grp * 16;

    for (int t = 0; t < LL; ++t) {
        const int idx = rev ? (LL - 1 - t) : t;
        float gir = 0.f, giz = 0.f, gin = 0.f;
        if (grp == 0) {
            gir = gi[idx * G3 + r3];
            giz = gi[idx * G3 + 256 + r3];
            gin = gi[idx * G3 + 512 + r3];
        }
        float acc0 = bias0, acc1 = bias1, acc2 = bias2;
        FOR16(DOTSTEP)
        if (grp == 1) {
            part[r3] = acc0; part[256 + r3] = acc1; part[512 + r3] = acc2;
        }
        __syncthreads();
        if (grp == 0) {
            float r = sigmoidf_(gir + acc0 + part[r3]);
            float z = sigmoidf_(giz + acc1 + part[256 + r3]);
            float n = tanhf_(gin + r * (acc2 + part[512 + r3]));
            hcur = (1.0f - z) * n + z * hcur;
            y[idx * TT + r3] = hcur;
            ((_Float16*)h_u32)[r3] = (_Float16)hcur;
        }
        __syncthreads();
    }
}

// ---------- Kernel E: attention scores alpha = vs @ v ----------
__global__ void k_alpha(const float* __restrict__ vs, const float* __restrict__ v,
                        float* __restrict__ alpha) {
    const int wv = threadIdx.x >> 6;
    const int lane = threadIdx.x & 63;
    const int n = blockIdx.x * 4 + wv;
    float4 a = ((const float4*)(vs + (size_t)n * TT))[lane];
    float4 b = ((const float4*)v)[lane];
    float p = a.x * b.x + a.y * b.y + a.z * b.z + a.w * b.w;
    #pragma unroll
    for (int off = 32; off; off >>= 1) p += __shfl_down(p, off, 64);
    if (lane == 0) alpha[n] = p;
}

// ---------- Kernel F1: step-GRU gates — one wave per row, coalesced ----------
__global__ void k_gates_s(const float* __restrict__ v, const float* __restrict__ score,
                          const float* __restrict__ hin,
                          const float* __restrict__ wihS, const float* __restrict__ bihS,
                          const float* __restrict__ whhS, const float* __restrict__ bhhS,
                          float* __restrict__ gis, float* __restrict__ ghs) {
    const int j = (blockIdx.x * blockDim.x + threadIdx.x) >> 6;  // wave id = row
    const int lane = threadIdx.x & 63;
    if (j >= G3) return;
    const float sc = score[0];
    const float gp = (sc >= 0.5f) ? 1.0f : 0.0f;
    const float gn = 1.0f - gp;
    const float* wi = wihS + (size_t)j * (2 * TT + 1);
    float a = 0.0f;
    #pragma unroll
    for (int k = 0; k < 8; ++k) {
        int c = lane + 64 * k;
        float x = (c < 256) ? v[c] * gp : v[c - 256] * gn;
        a += wi[c] * x;
    }
    if (lane == 0) a += wi[2 * TT] * sc;
    const float* wh = whhS + (size_t)j * SS;
    float g = 0.0f;
    #pragma unroll
    for (int k = 0; k < 4; ++k) {
        int c = lane + 64 * k;
        g += wh[c] * hin[c];
    }
    #pragma unroll
    for (int off = 32; off; off >>= 1) {
        a += __shfl_down(a, off, 64);
        g += __shfl_down(g, off, 64);
    }
    if (lane == 0) { gis[j] = a + bihS[j]; ghs[j] = g + bhhS[j]; }
}

// ---------- Kernel F2: top-k + softmax + attn + score head + h_new ----------
__global__ void k_head(const float* __restrict__ alpha_g, const float* __restrict__ v,
                       const float* __restrict__ hin, const float* __restrict__ hs,
                       const float* __restrict__ score_w, const float* __restrict__ score_b,
                       const float* __restrict__ gis, const float* __restrict__ ghs,
                       float* __restrict__ d_out, float* __restrict__ hnew_ws) {
    __shared__ float sa[NN];  // 32 KiB
    __shared__ float wbv[16];
    __shared__ int wbi[16];
    __shared__ float topv[KK];
    __shared__ int topi[KK];
    __shared__ float wk[KK];
    __shared__ float predv[G3 + 8];
    const int tid = threadIdx.x;
    for (int i = tid; i < NN; i += 1024) sa[i] = alpha_g[i];
    __syncthreads();
    for (int it = 0; it < KK; ++it) {
        float bv = -FLT_MAX; int bi = 0x7fffffff;
        #pragma unroll
        for (int k = 0; k < 8; ++k) {
            int i = tid + 1024 * k;
            float x = sa[i];
            if (x > bv) { bv = x; bi = i; }
        }
        #pragma unroll
        for (int off = 32; off; off >>= 1) {
            float ov = __shfl_down(bv, off, 64);
            int oi = __shfl_down(bi, off, 64);
            if (ov > bv || (ov == bv && oi < bi)) { bv = ov; bi = oi; }
        }
        const int lane = tid & 63, wv = tid >> 6;
        if (lane == 0) { wbv[wv] = bv; wbi[wv] = bi; }
        __syncthreads();
        if (tid == 0) {
            float Bv = wbv[0]; int Bi = wbi[0];
            for (int wq = 1; wq < 16; ++wq)
                if (wbv[wq] > Bv || (wbv[wq] == Bv && wbi[wq] < Bi)) { Bv = wbv[wq]; Bi = wbi[wq]; }
            topv[it] = Bv; topi[it] = Bi;
            sa[Bi] = -FLT_MAX;
        }
        __syncthreads();
    }
    if (tid == 0) {
        float m = topv[0], s = 0.0f, e[KK];
        for (int k = 0; k < KK; ++k) { e[k] = __expf(topv[k] - m); s += e[k]; }
        float rs = 1.0f / s;
        for (int k = 0; k < KK; ++k) wk[k] = e[k] * rs;
    }
    __syncthreads();
    if (tid < TT) {
        float ah = 0.0f;
        #pragma unroll
        for (int k = 0; k < KK; ++k) ah += wk[k] * hs[(size_t)topi[k] * SS + tid];
        predv[tid] = v[tid];
        predv[TT + tid] = ah;
        predv[2 * TT + tid] = hin[tid];
        if (tid == 0) predv[G3] = (float)KK;
    }
    __syncthreads();
    if (tid < 64) {
        float p = 0.0f;
        for (int c = tid; c < G3 + 1; c += 64) p += predv[c] * score_w[c];
        #pragma unroll
        for (int off = 32; off; off >>= 1) p += __shfl_down(p, off, 64);
        if (tid == 0) d_out[0] = p + score_b[0];
    }
    if (tid < SS) {
        const int i = tid;
        float r = sigmoidf_(gis[i] + ghs[i]);
        float z = sigmoidf_(gis[TT + i] + ghs[TT + i]);
        float n = tanhf_(gis[2 * TT + i] + r * ghs[2 * TT + i]);
        float hn = (1.0f - z) * n + z * hin[i];
        d_out[1 + i] = hn;
        hnew_ws[i] = hn;
    }
}

// ---------- Kernel G: cache copies + appends ----------
__global__ void k_finalize(const float* __restrict__ vs, const float* __restrict__ hs,
                           const float* __restrict__ v, const float* __restrict__ hnew,
                           float* __restrict__ d_out) {
    const size_t i = (size_t)blockIdx.x * blockDim.x + threadIdx.x;
    const size_t stride = (size_t)gridDim.x * blockDim.x;
    float* vs_out = d_out + 1 + TT;
    float* hs_out = vs_out + (size_t)(NN + 1) * TT;
    for (size_t x = i; x < (size_t)NN * TT; x += stride) vs_out[x] = vs[x];
    for (size_t x = i; x < (size_t)NN * SS; x += stride) hs_out[x] = hs[x];
    if (i < TT) vs_out[(size_t)NN * TT + i] = v[i];
    if (i < SS) hs_out[(size_t)NN * SS + i] = hnew[i];
}

extern "C" void kernel_launch(void* const* d_in, const int* in_sizes, int n_in,
                              void* d_out, int out_size, void* d_ws, size_t ws_size,
                              hipStream_t stream) {
    (void)in_sizes; (void)n_in; (void)out_size; (void)ws_size;
    const int* topic = (const int*)d_in[0];
    const float* score = (const float*)d_in[1];
    const float* hin = (const float*)d_in[3];
    const float* vs = (const float*)d_in[4];
    const float* hs = (const float*)d_in[5];
    const float* emb = (const float*)d_in[6];
    const float* wihF = (const float*)d_in[7];
    const float* whhF = (const float*)d_in[8];
    const float* bihF = (const float*)d_in[9];
    const float* bhhF = (const float*)d_in[10];
    const float* wihB = (const float*)d_in[11];
    const float* whhB = (const float*)d_in[12];
    const float* bihB = (const float*)d_in[13];
    const float* bhhB = (const float*)d_in[14];
    const float* wihO = (const float*)d_in[15];
    const float* whhO = (const float*)d_in[16];
    const float* bihO = (const float*)d_in[17];
    const float* bhhO = (const float*)d_in[18];
    const float* wihS = (const float*)d_in[19];
    const float* whhS = (const float*)d_in[20];
    const float* bihS = (const float*)d_in[21];
    const float* bhhS = (const float*)d_in[22];
    const float* scw = (const float*)d_in[23];
    const float* scb = (const float*)d_in[24];

    float* ws = (float*)d_ws;
    float* giF = ws;                     // 128*768
    float* giB = giF + LL * G3;
    float* yF  = giB + LL * G3;          // 128*256
    float* yB  = yF + LL * TT;
    float* giO = yB + LL * TT;           // 128*768
    float* yO  = giO + LL * G3;          // 128*256
    float* alpha = yO + LL * TT;         // 8192
    float* gis = alpha + NN;             // 768
    float* ghs = gis + G3;               // 768
    float* hnew = ghs + G3;              // 256
    unsigned int* pF = (unsigned int*)(hnew + TT);
    unsigned int* pB = pF + PKN;
    unsigned int* pO = pB + PKN;
    float* out = (float*)d_out;
    const float* v = yO + 127 * TT;      // topic_v[0]

    k_pack<<<dim3(96, 3), 1024, 0, stream>>>(whhF, whhB, whhO, pF, pB, pO);
    k_input_gates_word<<<dim3(LL, 2), G3, 0, stream>>>(topic, emb, wihF, bihF, wihB, bihB, giF, giB);
    k_gru_scan<<<2, 512, 0, stream>>>(giF, pF, bhhF, yF, 0, giB, pB, bhhB, yB, 1);
    k_input_gates_out<<<LL, G3, 0, stream>>>(yF, yB, wihO, bihO, giO);
    k_gru_scan<<<1, 512, 0, stream>>>(giO, pO, bhhO, yO, 0, giO, pO, bhhO, yO, 0);
    k_alpha<<<NN / 4, 256, 0, stream>>>(vs, v, alpha);
    k_gates_s<<<G3 / 4, 256, 0, stream>>>(v, score, hin, wihS, bihS, whhS, bhhS, gis, ghs);
    k_head<<<1, 1024, 0, stream>>>(alpha, v, hin, hs, scw, scb, gis, ghs, out, hnew);
    k_finalize<<<2048, 256, 0, stream>>>(vs, hs, v, hnew, out);
}

// Round 11
// 616.765 us; speedup vs baseline: 1.2152x; 1.2152x over previous
//
#include <hip/hip_runtime.h>
#include <cfloat>

#define EMB 300
#define TT 256      // T (word/output GRU hidden, also S)
#define SS 256      // S
#define KK 10
#define LL 128
#define NN 8192
#define G3 768      // 3*T
#define PKN (1024 * 96)   // u32 count of one packed whh (per-scan)

typedef _Float16 half2_t __attribute__((ext_vector_type(2)));

#if __has_builtin(__builtin_amdgcn_fdot2)
#define FDOT2(a, b, c) __builtin_amdgcn_fdot2((a), (b), (c), false)
#else
#define FDOT2(a, b, c) ((c) + (float)(a).x * (float)(b).x + (float)(a).y * (float)(b).y)
#endif

__device__ __forceinline__ float sigmoidf_(float x) {
    return __builtin_amdgcn_rcpf(1.0f + __expf(-x));
}
__device__ __forceinline__ float tanhf_(float x) {
    return 2.0f * __builtin_amdgcn_rcpf(1.0f + __expf(-2.0f * x)) - 1.0f;
}

// ---------- Kernel P: pack whh f32 -> f16-pair u32, per-thread-consumption order ----
// Scan thread tid (0..1023): grp=tid>>8 (k-quarter), r3=tid&255.
// Rows: rr*256+r3 (gate-major), rr in [0,3). Per-thread u32 idx: rr*32 + c*4 + q,
// c in [0,8), q in [0,4). Source: whh[(rr*256+r3)*256 + grp*64 + c*8 + q*2 + {0,1}].
__global__ void k_pack(const float* __restrict__ whhF, const float* __restrict__ whhB,
                       const float* __restrict__ whhO, unsigned int* __restrict__ pF,
                       unsigned int* __restrict__ pB, unsigned int* __restrict__ pO) {
    const int m = blockIdx.y;
    const float* src = m == 0 ? whhF : (m == 1 ? whhB : whhO);
    unsigned int* dst = m == 0 ? pF : (m == 1 ? pB : pO);
    const int g = blockIdx.x * 1024 + threadIdx.x;  // [0, 98304)
    const int tid_s = g / 96;
    const int idx = g - tid_s * 96;
    const int rr = idx >> 5;
    const int c = (idx >> 2) & 7;
    const int q = idx & 3;
    const int grp = tid_s >> 8;
    const int r3 = tid_s & 255;
    const int row = rr * 256 + r3;
    const int kb = grp * 64 + c * 8 + q * 2;
    const float e0 = src[row * 256 + kb];
    const float e1 = src[row * 256 + kb + 1];
    unsigned int lo = (unsigned int)__builtin_bit_cast(unsigned short, (_Float16)e0);
    unsigned int hi = (unsigned int)__builtin_bit_cast(unsigned short, (_Float16)e1);
    dst[g] = lo | (hi << 16);
}

// ---------- Kernel A: word-GRU input gates for both directions ----------
__global__ void k_input_gates_word(const int* __restrict__ topic, const float* __restrict__ emb,
                                   const float* __restrict__ wihF, const float* __restrict__ bihF,
                                   const float* __restrict__ wihB, const float* __restrict__ bihB,
                                   float* __restrict__ giF, float* __restrict__ giB) {
    __shared__ float4 xl[EMB / 4];  // 75
    const int l = blockIdx.x;
    const int dir = blockIdx.y;
    const float* wih = dir ? wihB : wihF;
    const float* bih = dir ? bihB : bihF;
    float* gi = dir ? giB : giF;
    const int word = topic[l];
    const float4* xrow = (const float4*)(emb + (size_t)word * EMB);
    if (threadIdx.x < EMB / 4) xl[threadIdx.x] = xrow[threadIdx.x];
    __syncthreads();
    const int j = threadIdx.x;  // 0..767
    const float4* wr = (const float4*)(wih + (size_t)j * EMB);
    float acc = bih[j];
    #pragma unroll 5
    for (int c = 0; c < EMB / 4; ++c) {
        float4 w4 = wr[c], x4 = xl[c];
        acc += w4.x * x4.x + w4.y * x4.y + w4.z * x4.z + w4.w * x4.w;
    }
    gi[l * G3 + j] = acc;
}

// ---------- Kernel C: output-GRU input gates ----------
__global__ void k_input_gates_out(const float* __restrict__ yF, const float* __restrict__ yB,
                                  const float* __restrict__ wihO, const float* __restrict__ bihO,
                                  float* __restrict__ giO) {
    __shared__ float4 yl[128];  // 512 floats = [yf | yb]
    const int l = blockIdx.x;
    if (threadIdx.x < 64) {
        yl[threadIdx.x] = ((const float4*)(yF + l * TT))[threadIdx.x];
        yl[64 + threadIdx.x] = ((const float4*)(yB + l * TT))[threadIdx.x];
    }
    __syncthreads();
    const int j = threadIdx.x;
    const float4* wr = (const float4*)(wihO + (size_t)j * 512);
    float acc = bihO[j];
    #pragma unroll 4
    for (int c = 0; c < 128; ++c) {
        float4 w4 = wr[c], x4 = yl[c];
        acc += w4.x * x4.x + w4.y * x4.y + w4.z * x4.z + w4.w * x4.w;
    }
    giO[l * G3 + j] = acc;
}

// ---------- Kernel B: GRU recurrence, one block per scan ----------
// 1024 threads; grp = tid>>8 is k-QUARTER (4-way); r3 = tid&255 owns gate rows
// {r3, 256+r3, 512+r3}. Each thread holds only 96 weight dwords (24 uint4) --
// far below the ~512-reg budget at __launch_bounds__(1024,4), so the allocator
// keeps them VGPR-resident naturally (R3-R8 lesson: at 512thr/192dw the demand
// sat AT the 256-reg cliff and the allocator rematerialized from L2 every step
// -> L2-BW-bound ~2700cyc/step; pins made it worse). No pins needed here.
#define FOR8(M) M(0) M(1) M(2) M(3) M(4) M(5) M(6) M(7)

#define LOADW(n) uint4 A##n = wp[n]; uint4 B##n = wp[8 + n]; uint4 C##n = wp[16 + n];

#define DOTSTEP(n) { \
    uint4 hu = h4[n]; \
    half2_t h0 = __builtin_bit_cast(half2_t, hu.x); \
    half2_t h1 = __builtin_bit_cast(half2_t, hu.y); \
    half2_t h2 = __builtin_bit_cast(half2_t, hu.z); \
    half2_t h3 = __builtin_bit_cast(half2_t, hu.w); \
    acc0 = FDOT2(__builtin_bit_cast(half2_t, A##n.x), h0, acc0); \
    acc1 = FDOT2(__builtin_bit_cast(half2_t, B##n.x), h0, acc1); \
    acc2 = FDOT2(__builtin_bit_cast(half2_t, C##n.x), h0, acc2); \
    acc0 = FDOT2(__builtin_bit_cast(half2_t, A##n.y), h1, acc0); \
    acc1 = FDOT2(__builtin_bit_cast(half2_t, B##n.y), h1, acc1); \
    acc2 = FDOT2(__builtin_bit_cast(half2_t, C##n.y), h1, acc2); \
    acc0 = FDOT2(__builtin_bit_cast(half2_t, A##n.z), h2, acc0); \
    acc1 = FDOT2(__builtin_bit_cast(half2_t, B##n.z), h2, acc1); \
    acc2 = FDOT2(__builtin_bit_cast(half2_t, C##n.z), h2, acc2); \
    acc0 = FDOT2(__builtin_bit_cast(half2_t, A##n.w), h3, acc0); \
    acc1 = FDOT2(__builtin_bit_cast(half2_t, B##n.w), h3, acc1); \
    acc2 = FDOT2(__builtin_bit_cast(half2_t, C##n.w), h3, acc2); \
}

__launch_bounds__(1024, 4)
__global__ void k_gru_scan(const float* __restrict__ giA, const unsigned int* __restrict__ pA,
                           const float* __restrict__ bhhA, float* __restrict__ yA, int revA,
                           const float* __restrict__ giB_, const unsigned int* __restrict__ pB,
                           const float* __restrict__ bhhB, float* __restrict__ yB_, int revB) {
    const float* gi; const unsigned int* pk; const float* bhh; float* y; int rev;
    if (blockIdx.x == 0) { gi = giA;  pk = pA; bhh = bhhA; y = yA;  rev = revA; }
    else                 { gi = giB_; pk = pB; bhh = bhhB; y = yB_; rev = revB; }

    __shared__ __align__(16) unsigned int h_u32[TT / 2];  // h as f16 pairs (512 B)
    __shared__ float part[3 * G3];                         // grp1..3 partials (9 KB)

    const int tid = threadIdx.x;
    const int grp = tid >> 8;   // k-quarter 0..3
    const int r3 = tid & 255;

    // --- load packed weights into 24 named uint4 values (96 dwords) ---
    const uint4* wp = (const uint4*)(pk + (size_t)tid * 96);
    FOR8(LOADW)

    float bias0 = 0.f, bias1 = 0.f, bias2 = 0.f;
    if (grp == 0) { bias0 = bhh[r3]; bias1 = bhh[256 + r3]; bias2 = bhh[512 + r3]; }

    for (int i = tid; i < TT / 2; i += 1024) h_u32[i] = 0u;
    float hcur = 0.0f;
    __syncthreads();

    const uint4* h4 = ((const uint4*)h_u32) + grp * 8;  // this quarter's 8 uint4

    for (int t = 0; t < LL; ++t) {
        const int idx = rev ? (LL - 1 - t) : t;
        float gir = 0.f, giz = 0.f, gin = 0.f;
        if (grp == 0) {
            gir = gi[idx * G3 + r3];
            giz = gi[idx * G3 + 256 + r3];
            gin = gi[idx * G3 + 512 + r3];
        }
        float acc0 = bias0, acc1 = bias1, acc2 = bias2;
        FOR8(DOTSTEP)
        if (grp > 0) {
            float* pg = part + (grp - 1) * G3;
            pg[r3] = acc0; pg[256 + r3] = acc1; pg[512 + r3] = acc2;
        }
        __syncthreads();
        if (grp == 0) {
            float s0 = acc0 + part[r3]       + part[G3 + r3]       + part[2 * G3 + r3];
            float s1 = acc1 + part[256 + r3] + part[G3 + 256 + r3] + part[2 * G3 + 256 + r3];
            float s2 = acc2 + part[512 + r3] + part[G3 + 512 + r3] + part[2 * G3 + 512 + r3];
            float r = sigmoidf_(gir + s0);
            float z = sigmoidf_(giz + s1);
            float n = tanhf_(gin + r * s2);
            hcur = (1.0f - z) * n + z * hcur;
            y[idx * TT + r3] = hcur;
            ((_Float16*)h_u32)[r3] = (_Float16)hcur;
        }
        __syncthreads();
    }
}

// ---------- Kernel E: attention scores alpha = vs @ v ----------
__global__ void k_alpha(const float* __restrict__ vs, const float* __restrict__ v,
                        float* __restrict__ alpha) {
    const int wv = threadIdx.x >> 6;
    const int lane = threadIdx.x & 63;
    const int n = blockIdx.x * 4 + wv;
    float4 a = ((const float4*)(vs + (size_t)n * TT))[lane];
    float4 b = ((const float4*)v)[lane];
    float p = a.x * b.x + a.y * b.y + a.z * b.z + a.w * b.w;
    #pragma unroll
    for (int off = 32; off; off >>= 1) p += __shfl_down(p, off, 64);
    if (lane == 0) alpha[n] = p;
}

// ---------- Kernel F1: step-GRU gates — one wave per row, coalesced ----------
__global__ void k_gates_s(const float* __restrict__ v, const float* __restrict__ score,
                          const float* __restrict__ hin,
                          const float* __restrict__ wihS, const float* __restrict__ bihS,
                          const float* __restrict__ whhS, const float* __restrict__ bhhS,
                          float* __restrict__ gis, float* __restrict__ ghs) {
    const int j = (blockIdx.x * blockDim.x + threadIdx.x) >> 6;  // wave id = row
    const int lane = threadIdx.x & 63;
    if (j >= G3) return;
    const float sc = score[0];
    const float gp = (sc >= 0.5f) ? 1.0f : 0.0f;
    const float gn = 1.0f - gp;
    const float* wi = wihS + (size_t)j * (2 * TT + 1);
    float a = 0.0f;
    #pragma unroll
    for (int k = 0; k < 8; ++k) {
        int c = lane + 64 * k;
        float x = (c < 256) ? v[c] * gp : v[c - 256] * gn;
        a += wi[c] * x;
    }
    if (lane == 0) a += wi[2 * TT] * sc;
    const float* wh = whhS + (size_t)j * SS;
    float g = 0.0f;
    #pragma unroll
    for (int k = 0; k < 4; ++k) {
        int c = lane + 64 * k;
        g += wh[c] * hin[c];
    }
    #pragma unroll
    for (int off = 32; off; off >>= 1) {
        a += __shfl_down(a, off, 64);
        g += __shfl_down(g, off, 64);
    }
    if (lane == 0) { gis[j] = a + bihS[j]; ghs[j] = g + bhhS[j]; }
}

// ---------- Kernel F2: top-k + softmax + attn + score head + h_new ----------
__global__ void k_head(const float* __restrict__ alpha_g, const float* __restrict__ v,
                       const float* __restrict__ hin, const float* __restrict__ hs,
                       const float* __restrict__ score_w, const float* __restrict__ score_b,
                       const float* __restrict__ gis, const float* __restrict__ ghs,
                       float* __restrict__ d_out, float* __restrict__ hnew_ws) {
    __shared__ float sa[NN];  // 32 KiB
    __shared__ float wbv[16];
    __shared__ int wbi[16];
    __shared__ float topv[KK];
    __shared__ int topi[KK];
    __shared__ float wk[KK];
    __shared__ float predv[G3 + 8];
    const int tid = threadIdx.x;
    for (int i = tid; i < NN; i += 1024) sa[i] = alpha_g[i];
    __syncthreads();
    for (int it = 0; it < KK; ++it) {
        float bv = -FLT_MAX; int bi = 0x7fffffff;
        #pragma unroll
        for (int k = 0; k < 8; ++k) {
            int i = tid + 1024 * k;
            float x = sa[i];
            if (x > bv) { bv = x; bi = i; }
        }
        #pragma unroll
        for (int off = 32; off; off >>= 1) {
            float ov = __shfl_down(bv, off, 64);
            int oi = __shfl_down(bi, off, 64);
            if (ov > bv || (ov == bv && oi < bi)) { bv = ov; bi = oi; }
        }
        const int lane = tid & 63, wv = tid >> 6;
        if (lane == 0) { wbv[wv] = bv; wbi[wv] = bi; }
        __syncthreads();
        if (tid == 0) {
            float Bv = wbv[0]; int Bi = wbi[0];
            for (int wq = 1; wq < 16; ++wq)
                if (wbv[wq] > Bv || (wbv[wq] == Bv && wbi[wq] < Bi)) { Bv = wbv[wq]; Bi = wbi[wq]; }
            topv[it] = Bv; topi[it] = Bi;
            sa[Bi] = -FLT_MAX;
        }
        __syncthreads();
    }
    if (tid == 0) {
        float m = topv[0], s = 0.0f, e[KK];
        for (int k = 0; k < KK; ++k) { e[k] = __expf(topv[k] - m); s += e[k]; }
        float rs = 1.0f / s;
        for (int k = 0; k < KK; ++k) wk[k] = e[k] * rs;
    }
    __syncthreads();
    if (tid < TT) {
        float ah = 0.0f;
        #pragma unroll
        for (int k = 0; k < KK; ++k) ah += wk[k] * hs[(size_t)topi[k] * SS + tid];
        predv[tid] = v[tid];
        predv[TT + tid] = ah;
        predv[2 * TT + tid] = hin[tid];
        if (tid == 0) predv[G3] = (float)KK;
    }
    __syncthreads();
    if (tid < 64) {
        float p = 0.0f;
        for (int c = tid; c < G3 + 1; c += 64) p += predv[c] * score_w[c];
        #pragma unroll
        for (int off = 32; off; off >>= 1) p += __shfl_down(p, off, 64);
        if (tid == 0) d_out[0] = p + score_b[0];
    }
    if (tid < SS) {
        const int i = tid;
        float r = sigmoidf_(gis[i] + ghs[i]);
        float z = sigmoidf_(gis[TT + i] + ghs[TT + i]);
        float n = tanhf_(gis[2 * TT + i] + r * ghs[2 * TT + i]);
        float hn = (1.0f - z) * n + z * hin[i];
        d_out[1 + i] = hn;
        hnew_ws[i] = hn;
    }
}

// ---------- Kernel G: cache copies + appends ----------
__global__ void k_finalize(const float* __restrict__ vs, const float* __restrict__ hs,
                           const float* __restrict__ v, const float* __restrict__ hnew,
                           float* __restrict__ d_out) {
    const size_t i = (size_t)blockIdx.x * blockDim.x + threadIdx.x;
    const size_t stride = (size_t)gridDim.x * blockDim.x;
    float* vs_out = d_out + 1 + TT;
    float* hs_out = vs_out + (size_t)(NN + 1) * TT;
    for (size_t x = i; x < (size_t)NN * TT; x += stride) vs_out[x] = vs[x];
    for (size_t x = i; x < (size_t)NN * SS; x += stride) hs_out[x] = hs[x];
    if (i < TT) vs_out[(size_t)NN * TT + i] = v[i];
    if (i < SS) hs_out[(size_t)NN * SS + i] = hnew[i];
}

extern "C" void kernel_launch(void* const* d_in, const int* in_sizes, int n_in,
                              void* d_out, int out_size, void* d_ws, size_t ws_size,
                              hipStream_t stream) {
    (void)in_sizes; (void)n_in; (void)out_size; (void)ws_size;
    const int* topic = (const int*)d_in[0];
    const float* score = (const float*)d_in[1];
    const float* hin = (const float*)d_in[3];
    const float* vs = (const float*)d_in[4];
    const float* hs = (const float*)d_in[5];
    const float* emb = (const float*)d_in[6];
    const float* wihF = (const float*)d_in[7];
    const float* whhF = (const float*)d_in[8];
    const float* bihF = (const float*)d_in[9];
    const float* bhhF = (const float*)d_in[10];
    const float* wihB = (const float*)d_in[11];
    const float* whhB = (const float*)d_in[12];
    const float* bihB = (const float*)d_in[13];
    const float* bhhB = (const float*)d_in[14];
    const float* wihO = (const float*)d_in[15];
    const float* whhO = (const float*)d_in[16];
    const float* bihO = (const float*)d_in[17];
    const float* bhhO = (const float*)d_in[18];
    const float* wihS = (const float*)d_in[19];
    const float* whhS = (const float*)d_in[20];
    const float* bihS = (const float*)d_in[21];
    const float* bhhS = (const float*)d_in[22];
    const float* scw = (const float*)d_in[23];
    const float* scb = (const float*)d_in[24];

    float* ws = (float*)d_ws;
    float* giF = ws;                     // 128*768
    float* giB = giF + LL * G3;
    float* yF  = giB + LL * G3;          // 128*256
    float* yB  = yF + LL * TT;
    float* giO = yB + LL * TT;           // 128*768
    float* yO  = giO + LL * G3;          // 128*256
    float* alpha = yO + LL * TT;         // 8192
    float* gis = alpha + NN;             // 768
    float* ghs = gis + G3;               // 768
    float* hnew = ghs + G3;              // 256
    unsigned int* pF = (unsigned int*)(hnew + TT);
    unsigned int* pB = pF + PKN;
    unsigned int* pO = pB + PKN;
    float* out = (float*)d_out;
    const float* v = yO + 127 * TT;      // topic_v[0]

    k_pack<<<dim3(96, 3), 1024, 0, stream>>>(whhF, whhB, whhO, pF, pB, pO);
    k_input_gates_word<<<dim3(LL, 2), G3, 0, stream>>>(topic, emb, wihF, bihF, wihB, bihB, giF, giB);
    k_gru_scan<<<2, 1024, 0, stream>>>(giF, pF, bhhF, yF, 0, giB, pB, bhhB, yB, 1);
    k_input_gates_out<<<LL, G3, 0, stream>>>(yF, yB, wihO, bihO, giO);
    k_gru_scan<<<1, 1024, 0, stream>>>(giO, pO, bhhO, yO, 0, giO, pO, bhhO, yO, 0);
    k_alpha<<<NN / 4, 256, 0, stream>>>(vs, v, alpha);
    k_gates_s<<<G3 / 4, 256, 0, stream>>>(v, score, hin, wihS, bihS, whhS, bhhS, gis, ghs);
    k_head<<<1, 1024, 0, stream>>>(alpha, v, hin, hs, scw, scb, gis, ghs, out, hnew);
    k_finalize<<<2048, 256, 0, stream>>>(vs, hs, v, hnew, out);
}